// Round 4
// baseline (3107.110 us; speedup 1.0000x reference)
//
#include <hip/hip_runtime.h>
#include <hip/hip_bf16.h>

typedef __bf16 bf16_t;
typedef __bf16 bf16x4 __attribute__((ext_vector_type(4)));
typedef __bf16 bf16x8 __attribute__((ext_vector_type(8)));
typedef float f32x4 __attribute__((ext_vector_type(4)));

constexpr int T_STEPS = 50;
constexpr int B_SZ = 1024;
constexpr int NP_SZ = 512;
constexpr int NH_SZ = 512;
constexpr int NG_SZ = 4096;

// async 16B/lane global->LDS; lds base must be wave-uniform (HW: base + lane*16)
__device__ __forceinline__ void async16(const bf16_t* g, bf16_t* l) {
    __builtin_amdgcn_global_load_lds((const __attribute__((address_space(1))) void*)g,
                                     (__attribute__((address_space(3))) void*)l, 16, 0, 0);
}

__device__ __forceinline__ float fsig(float x) { return 1.f / (1.f + __expf(-x)); }
__device__ __forceinline__ float ftanh(float x) { return 2.f / (1.f + __expf(-2.f * x)) - 1.f; }

// ---------------- fp32 -> bf16 convert ----------------
__global__ __launch_bounds__(256) void cvt_f32_bf16(const float* __restrict__ src,
                                                    bf16_t* __restrict__ dst, int n4) {
    int i = blockIdx.x * blockDim.x + threadIdx.x;
    if (i >= n4) return;
    float4 v = ((const float4*)src)[i];
    bf16x4 o;
    o[0] = (bf16_t)v.x; o[1] = (bf16_t)v.y; o[2] = (bf16_t)v.z; o[3] = (bf16_t)v.w;
    ((bf16x4*)dst)[i] = o;
}

// ---------------- dbuf MFMA GEMM: C = ep(A[M,K] @ B[N,K]^T) ----------------
// EP: 0 = +bias f32 out | 1 = +bias bf16 out | 2 = relu bf16 out
template <int BM, int BN, int EP>
__global__ __launch_bounds__(256) void gemm16(const bf16_t* __restrict__ A,
                                              const bf16_t* __restrict__ Bm,
                                              const float* __restrict__ bias,
                                              void* __restrict__ Cout, int M, int N, int K) {
    constexpr int ASUB = BM / 16, BSUB = BN / 16, NSUB = ASUB + BSUB;
    static_assert(NSUB % 4 == 0, "subtile split");
    constexpr int PW = NSUB / 4;
    constexpr int MT = BM / 32, NT = BN / 32;
    constexpr int BUF = NSUB * 512;
    __shared__ bf16_t lds[2 * BUF];

    const int tid = threadIdx.x, lane = tid & 63, wave = tid >> 6;
    const int wm = wave >> 1, wn = wave & 1;
    const int l15 = lane & 15, quad = lane >> 4;
    const int bm0 = blockIdx.y * BM, bn0 = blockIdx.x * BN;

    const bf16_t* gsrc[PW];
    int loff[PW];
#pragma unroll
    for (int q = 0; q < PW; q++) {
        int s = wave * PW + q;
        if (s < ASUB)
            gsrc[q] = A + (size_t)(bm0 + s * 16 + l15) * K + quad * 8;
        else
            gsrc[q] = Bm + (size_t)(bn0 + (s - ASUB) * 16 + l15) * K + quad * 8;
        loff[q] = s * 512;
    }

    f32x4 acc[MT][NT];
#pragma unroll
    for (int i = 0; i < MT; i++)
#pragma unroll
        for (int j = 0; j < NT; j++) acc[i][j] = f32x4{0.f, 0.f, 0.f, 0.f};

    const int KC = K >> 5;
#pragma unroll
    for (int q = 0; q < PW; q++) async16(gsrc[q], &lds[loff[q]]);

    for (int kc = 0; kc < KC; kc++) {
        const bf16_t* cur = &lds[(kc & 1) * BUF];
        __syncthreads();  // drains cur's loads; prior reads of nxt buffer done
        if (kc + 1 < KC) {
            bf16_t* nxt = &lds[((kc + 1) & 1) * BUF];
#pragma unroll
            for (int q = 0; q < PW; q++) async16(gsrc[q] + (kc + 1) * 32, nxt + loff[q]);
        }
        bf16x8 af[MT], bfg[NT];
#pragma unroll
        for (int i = 0; i < MT; i++)
            af[i] = *(const bf16x8*)&cur[(wm * MT + i) * 512 + lane * 8];
#pragma unroll
        for (int j = 0; j < NT; j++)
            bfg[j] = *(const bf16x8*)&cur[(ASUB + wn * NT + j) * 512 + lane * 8];
#pragma unroll
        for (int i = 0; i < MT; i++)
#pragma unroll
            for (int j = 0; j < NT; j++)
                acc[i][j] = __builtin_amdgcn_mfma_f32_16x16x32_bf16(af[i], bfg[j], acc[i][j], 0, 0, 0);
    }

#pragma unroll
    for (int j = 0; j < NT; j++) {
        const int col = bn0 + wn * (BN / 2) + j * 16 + l15;
        float bb = (EP == 2) ? 0.f : bias[col];
#pragma unroll
        for (int i = 0; i < MT; i++) {
#pragma unroll
            for (int r = 0; r < 4; r++) {
                const int row = bm0 + wm * (BM / 2) + i * 16 + quad * 4 + r;
                float x = acc[i][j][r];
                if constexpr (EP == 0) {
                    ((float*)Cout)[(size_t)row * N + col] = x + bb;
                } else if constexpr (EP == 1) {
                    ((bf16_t*)Cout)[(size_t)row * N + col] = (bf16_t)(x + bb);
                } else {
                    ((bf16_t*)Cout)[(size_t)row * N + col] = (bf16_t)fmaxf(x, 0.f);
                }
            }
        }
    }
}

// ---------------- device-scope grid barrier (regular launch, 256 co-resident blocks) ----------------
__device__ __forceinline__ void grid_bar(unsigned* bar, unsigned nblk) {
    __syncthreads();
    if (threadIdx.x == 0) {
        __threadfence();  // release: L2 writeback, agent scope
        unsigned g = __hip_atomic_load(bar + 1, __ATOMIC_RELAXED, __HIP_MEMORY_SCOPE_AGENT);
        unsigned a = __hip_atomic_fetch_add(bar, 1u, __ATOMIC_ACQ_REL, __HIP_MEMORY_SCOPE_AGENT);
        if (a == nblk - 1) {
            __hip_atomic_store(bar, 0u, __ATOMIC_RELAXED, __HIP_MEMORY_SCOPE_AGENT);
            __hip_atomic_store(bar + 1, g + 1u, __ATOMIC_RELEASE, __HIP_MEMORY_SCOPE_AGENT);
        } else {
            while (__hip_atomic_load(bar + 1, __ATOMIC_ACQUIRE, __HIP_MEMORY_SCOPE_AGENT) == g)
                __builtin_amdgcn_s_sleep(2);
        }
        __threadfence();  // acquire: invalidate stale cache before next step reads
    }
    __syncthreads();
}

// ---------------- persistent LSTM recurrence (regular launch + own barrier) ----------------
// 256 blocks x 256 thr, 1 block/CU (co-residency resource-guaranteed: no LDS, VGPR<=512).
// Block: 64 rows x 32 n-cols. Wave(wm,wn): rows r0+32*wm..+32, cols c0+16*wn..+16, all 4 gates.
// w_hh fragments for the block's cols live in REGISTERS across all 50 steps (16 kchunks x
// 4 gates x bf16x8 = 256 VGPRs) -> per step only hx is re-read (depth-8 register prefetch).
__global__ __launch_bounds__(256) void lstm_seq(
    const bf16_t* __restrict__ whh, const float* __restrict__ v,
    const float* __restrict__ wih, const float* __restrict__ bih,
    const float* __restrict__ bhh, const float* __restrict__ cx0,
    bf16_t* __restrict__ hx_seq, unsigned* __restrict__ bar) {
    const int tid = threadIdx.x, lane = tid & 63, wave = tid >> 6;
    const int wm = wave >> 1, wn = wave & 1;
    const int l15 = lane & 15, quad = lane >> 4;
    // XCD swizzle: blocks sharing an A(row)-slice land on the same XCD (blockIdx % 8 heuristic)
    const int xcd = blockIdx.x & 7, sidx = blockIdx.x >> 3;
    const int rb = xcd * 2 + (sidx & 1);  // 0..15
    const int cb = sidx >> 1;             // 0..15
    const int r0 = rb * 64, c0 = cb * 32;
    const int colg = c0 + 16 * wn + l15;

    // B (w_hh) fragments: resident in registers for the whole kernel
    bf16x8 Bs[16][4];
#pragma unroll
    for (int g = 0; g < 4; g++) {
        const bf16_t* bp = whh + (size_t)(g * NH_SZ + colg) * NH_SZ + quad * 8;
#pragma unroll
        for (int kc = 0; kc < 16; kc++) Bs[kc][g] = *(const bf16x8*)(bp + kc * 32);
    }

    float bi[4], w0[4], w1[4];
#pragma unroll
    for (int g = 0; g < 4; g++) {
        int gc = g * NH_SZ + colg;
        bi[g] = bih[gc] + bhh[gc];
        w0[g] = wih[gc * 2];
        w1[g] = wih[gc * 2 + 1];
    }

    const size_t arow0 = (size_t)(r0 + 32 * wm + l15) * NH_SZ + quad * 8;
    const size_t arow1 = arow0 + 16 * NH_SZ;

    float cxr[2][4];
#pragma unroll
    for (int i = 0; i < 2; i++)
#pragma unroll
        for (int r = 0; r < 4; r++) {
            int row = r0 + 32 * wm + 16 * i + quad * 4 + r;
            cxr[i][r] = cx0[(size_t)row * NH_SZ + colg];
        }

    for (int t = 0; t < T_STEPS; t++) {
        const bf16_t* hsrc = hx_seq + (size_t)t * B_SZ * NH_SZ;
        bf16x8 As[8][2];
#pragma unroll
        for (int p = 0; p < 7; p++) {  // prologue: chunks 0..6
            As[p][0] = *(const bf16x8*)(hsrc + arow0 + p * 32);
            As[p][1] = *(const bf16x8*)(hsrc + arow1 + p * 32);
        }
        f32x4 acc[4][2];
#pragma unroll
        for (int g = 0; g < 4; g++)
#pragma unroll
            for (int i = 0; i < 2; i++) acc[g][i] = f32x4{0.f, 0.f, 0.f, 0.f};

#pragma unroll
        for (int kc = 0; kc < 16; kc++) {
            if (kc + 7 < 16) {  // rolling depth-8 prefetch
                int sl = (kc + 7) & 7;
                As[sl][0] = *(const bf16x8*)(hsrc + arow0 + (kc + 7) * 32);
                As[sl][1] = *(const bf16x8*)(hsrc + arow1 + (kc + 7) * 32);
            }
            int cu = kc & 7;
#pragma unroll
            for (int g = 0; g < 4; g++)
#pragma unroll
                for (int i = 0; i < 2; i++)
                    acc[g][i] = __builtin_amdgcn_mfma_f32_16x16x32_bf16(As[cu][i], Bs[kc][g],
                                                                        acc[g][i], 0, 0, 0);
        }

        bf16_t* hdst = hx_seq + (size_t)(t + 1) * B_SZ * NH_SZ;
#pragma unroll
        for (int i = 0; i < 2; i++) {
#pragma unroll
            for (int r = 0; r < 4; r++) {
                const int row = r0 + 32 * wm + 16 * i + quad * 4 + r;
                const float* vp = v + ((size_t)t * B_SZ + row) * 2;
                float v0 = vp[0], v1 = vp[1];
                float xi = acc[0][i][r] + bi[0] + v0 * w0[0] + v1 * w1[0];
                float xf = acc[1][i][r] + bi[1] + v0 * w0[1] + v1 * w1[1];
                float xg = acc[2][i][r] + bi[2] + v0 * w0[2] + v1 * w1[2];
                float xo = acc[3][i][r] + bi[3] + v0 * w0[3] + v1 * w1[3];
                float c = fsig(xf) * cxr[i][r] + fsig(xi) * ftanh(xg);
                cxr[i][r] = c;
                hdst[(size_t)row * NH_SZ + colg] = (bf16_t)(fsig(xo) * ftanh(c));
            }
        }
        if (t + 1 < T_STEPS) grid_bar(bar, gridDim.x);
    }
}

// ---------------- host launcher ----------------
extern "C" void kernel_launch(void* const* d_in, const int* in_sizes, int n_in,
                              void* d_out, int out_size, void* d_ws, size_t ws_size,
                              hipStream_t stream) {
    const float* v    = (const float*)d_in[0];
    const float* p0   = (const float*)d_in[1];
    const float* e1w  = (const float*)d_in[2];
    const float* e1b  = (const float*)d_in[3];
    const float* e2w  = (const float*)d_in[4];
    const float* e2b  = (const float*)d_in[5];
    const float* wih  = (const float*)d_in[6];
    const float* whh  = (const float*)d_in[7];
    const float* bih  = (const float*)d_in[8];
    const float* bhh  = (const float*)d_in[9];
    const float* gw   = (const float*)d_in[10];
    const float* decw = (const float*)d_in[11];
    const float* decb = (const float*)d_in[12];
    float* out = (float*)d_out;

    size_t off = 0;
    auto take = [&](size_t bytes) {
        size_t o = off;
        off += (bytes + 255) & ~(size_t)255;
        return (void*)((char*)d_ws + o);
    };
    bf16_t*  p0b    = (bf16_t*)take((size_t)B_SZ * NP_SZ * 2);
    bf16_t*  e1wb   = (bf16_t*)take((size_t)NH_SZ * NP_SZ * 2);
    bf16_t*  e2wb   = (bf16_t*)take((size_t)NH_SZ * NP_SZ * 2);
    bf16_t*  whhb   = (bf16_t*)take((size_t)4 * NH_SZ * NH_SZ * 2);
    bf16_t*  gwb    = (bf16_t*)take((size_t)NG_SZ * NH_SZ * 2);
    bf16_t*  decwb  = (bf16_t*)take((size_t)NP_SZ * NG_SZ * 2);
    bf16_t*  hx_seq = (bf16_t*)take((size_t)(T_STEPS + 1) * B_SZ * NH_SZ * 2);
    float*   cx0f   = (float*)take((size_t)B_SZ * NH_SZ * 4);
    unsigned* bar   = (unsigned*)take(256);

    const size_t per_step = (size_t)B_SZ * NG_SZ * 2;  // 8 MB
    int C = 1;
    for (int c : {25, 10, 5, 2, 1}) {
        if (off + (size_t)c * per_step <= ws_size) { C = c; break; }
    }
    bf16_t* gbuf = (bf16_t*)take((size_t)C * per_step);

    hipMemsetAsync((void*)bar, 0, 64, stream);

    auto cvt = [&](const float* s, bf16_t* d, int n) {
        int n4 = n >> 2;
        cvt_f32_bf16<<<dim3((n4 + 255) / 256), dim3(256), 0, stream>>>(s, d, n4);
    };
    cvt(p0, p0b, B_SZ * NP_SZ);
    cvt(e1w, e1wb, NH_SZ * NP_SZ);
    cvt(e2w, e2wb, NH_SZ * NP_SZ);
    cvt(whh, whhb, 4 * NH_SZ * NH_SZ);
    cvt(gw, gwb, NG_SZ * NH_SZ);
    cvt(decw, decwb, NP_SZ * NG_SZ);

    // encoders -> hx_seq[0] (bf16) and cx0 (f32)
    gemm16<64, 64, 1><<<dim3(NH_SZ / 64, B_SZ / 64), 256, 0, stream>>>(
        p0b, e1wb, e1b, hx_seq, B_SZ, NH_SZ, NP_SZ);
    gemm16<64, 64, 0><<<dim3(NH_SZ / 64, B_SZ / 64), 256, 0, stream>>>(
        p0b, e2wb, e2b, cx0f, B_SZ, NH_SZ, NP_SZ);

    // persistent recurrence: regular launch, 256 blocks, own device-scope barrier
    lstm_seq<<<dim3(256), dim3(256), 0, stream>>>(whhb, v, wih, bih, bhh, cx0f, hx_seq, bar);

    // batched feed-forward in chunks of C steps
    for (int t0 = 0; t0 < T_STEPS; t0 += C) {
        const bf16_t* hA = hx_seq + (size_t)(t0 + 1) * B_SZ * NH_SZ;
        int M = C * B_SZ;
        gemm16<128, 128, 2><<<dim3(NG_SZ / 128, M / 128), 256, 0, stream>>>(
            hA, gwb, nullptr, gbuf, M, NG_SZ, NH_SZ);
        gemm16<128, 128, 0><<<dim3(NP_SZ / 128, M / 128), 256, 0, stream>>>(
            gbuf, decwb, decb, out + (size_t)t0 * B_SZ * NP_SZ, M, NP_SZ, NG_SZ);
    }
}